// Round 5
// baseline (397.909 us; speedup 1.0000x reference)
//
#include <hip/hip_runtime.h>
#include <stdint.h>

typedef float f32x4 __attribute__((ext_vector_type(4)));
typedef short bf16x8 __attribute__((ext_vector_type(8)));

constexpr int NB = 4;      // batch
constexpr int NS = 2048;   // sequence
constexpr int ND = 512;    // model dim
constexpr int NH = 8;      // heads
constexpr int NDK = 64;    // head dim
constexpr int NT = NS / 64;  // 32 K-tiles
constexpr float QSCALE = 0.125f * 1.44269504088896340736f;  // 1/sqrt(dk) * log2(e)

static __device__ __forceinline__ unsigned short f2bf(float f) {
    union { float f; uint32_t u; } v; v.f = f;
    uint32_t r = (v.u + 0x7FFFu + ((v.u >> 16) & 1u)) >> 16;
    return (unsigned short)r;
}
static __device__ __forceinline__ unsigned short f2bf_fast(float f) {
    union { float f; uint32_t u; } v; v.f = f;
    return (unsigned short)((v.u + 0x8000u) >> 16);
}
static __device__ __forceinline__ float exp2_fast(float x) {
#if __has_builtin(__builtin_amdgcn_exp2f)
    return __builtin_amdgcn_exp2f(x);
#else
    return exp2f(x);
#endif
}

// async global->LDS, 16B per lane; dest is wave-uniform base (+lane*16 by HW)
static __device__ __forceinline__ void gload_lds16(const void* g, void* l) {
    __builtin_amdgcn_global_load_lds((const __attribute__((address_space(1))) void*)g,
                                     (__attribute__((address_space(3))) void*)l, 16, 0, 0);
}

// ---------------- fp32 -> bf16 convert (3 tensors fused) ----------------
__global__ __launch_bounds__(256) void cvt3_kernel(const float4* __restrict__ a,
                                                   const float4* __restrict__ b,
                                                   const float4* __restrict__ c,
                                                   ushort4* __restrict__ oa,
                                                   ushort4* __restrict__ ob,
                                                   ushort4* __restrict__ oc, int n4) {
    int which = blockIdx.y;
    const float4* in = which == 0 ? a : which == 1 ? b : c;
    ushort4* out = which == 0 ? oa : which == 1 ? ob : oc;
    int i = blockIdx.x * blockDim.x + threadIdx.x;
    if (i >= n4) return;
    float4 v = in[i];
    ushort4 o;
    o.x = f2bf(v.x); o.y = f2bf(v.y); o.z = f2bf(v.z); o.w = f2bf(v.w);
    out[i] = o;
}

// ---------------- mask int32 -> bitmask (1 bit per element) ----------------
__global__ __launch_bounds__(256) void bitmask_kernel(const int* __restrict__ mask,
                                                      unsigned long long* __restrict__ bm,
                                                      int nwords) {
    int lane = threadIdx.x & 63;
    int wave = threadIdx.x >> 6;
    int wgid = blockIdx.x * 4 + wave;
    int nw = gridDim.x * 4;
    for (int c = wgid; c < nwords; c += nw) {
        int v = mask[(size_t)c * 64 + lane];
        unsigned long long bits = __ballot(v != 0);
        if (lane == 0) bm[c] = bits;
    }
}

// ---------------- fused projections: z=0 Q (scale QSCALE), z=1 K, z=2 V (transposed out) -----
__global__ __launch_bounds__(256) void proj_kernel(const unsigned short* __restrict__ xq,
                                                   const unsigned short* __restrict__ xk,
                                                   const unsigned short* __restrict__ xv,
                                                   const unsigned short* __restrict__ wq,
                                                   const unsigned short* __restrict__ wk,
                                                   const unsigned short* __restrict__ wv,
                                                   const float* __restrict__ bq,
                                                   const float* __restrict__ bk,
                                                   const float* __restrict__ bv,
                                                   unsigned short* __restrict__ Qw,
                                                   unsigned short* __restrict__ Kw,
                                                   unsigned short* __restrict__ VTw) {
    int z = blockIdx.z;
    const unsigned short* X = z == 0 ? xq : z == 1 ? xk : xv;
    const unsigned short* W = z == 0 ? wq : z == 1 ? wk : wv;
    const float* bias = z == 0 ? bq : z == 1 ? bk : bv;
    unsigned short* out = z == 0 ? Qw : z == 1 ? Kw : VTw;
    float scale = z == 0 ? QSCALE : 1.0f;
    int vtrans = (z == 2);

    int lane = threadIdx.x & 63;
    int wave = threadIdx.x >> 6;
    int lrow = lane & 15, lgrp = lane >> 4;
    int m0 = blockIdx.x * 64 + wave * 16;
    int n0 = blockIdx.y * 64;

    f32x4 acc[4] = {{0.f,0.f,0.f,0.f},{0.f,0.f,0.f,0.f},{0.f,0.f,0.f,0.f},{0.f,0.f,0.f,0.f}};
    const unsigned short* xrow = X + (size_t)(m0 + lrow) * ND;
    for (int k = 0; k < ND; k += 32) {
        bf16x8 a = *(const bf16x8*)(xrow + k + lgrp * 8);
#pragma unroll
        for (int n = 0; n < 4; n++) {
            bf16x8 b = *(const bf16x8*)(W + (size_t)(n0 + n * 16 + lrow) * ND + k + lgrp * 8);
            acc[n] = __builtin_amdgcn_mfma_f32_16x16x32_bf16(a, b, acc[n], 0, 0, 0);
        }
    }
#pragma unroll
    for (int n = 0; n < 4; n++) {
        int col = n0 + n * 16 + lrow;
        int h = col >> 6, d = col & 63;
        float bv_ = bias[col];
#pragma unroll
        for (int j = 0; j < 4; j++) {
            int m = m0 + lgrp * 4 + j;
            int bidx = m >> 11, s = m & (NS - 1);
            float y = (acc[n][j] + bv_) * scale;
            size_t off = vtrans ? ((size_t)(bidx * NH + h) * NDK + d) * NS + s
                                : ((size_t)(bidx * NH + h) * NS + s) * NDK + d;
            out[off] = f2bf(y);
        }
    }
}

// ---------------- attention ----------------
// 512 threads = 8 waves; block owns 128 q-rows, full K range. Q pre-scaled by log2e/8,
// so scores are in log2 domain: p = exp2(sc + li[row]), li = -log2(sum).
// K/V staged in LDS via global_load_lds, double-buffered, XOR-swizzled.
// attn stores deferred one tile so the barrier's vmcnt(0) drain doesn't eat the store tail.
__global__ __launch_bounds__(512) void attn_kernel(const unsigned short* __restrict__ Q,
                                                   const unsigned short* __restrict__ K,
                                                   const unsigned short* __restrict__ VT,
                                                   const unsigned long long* __restrict__ bm,
                                                   float* __restrict__ attn_out,
                                                   float* __restrict__ Ob) {
    __shared__ __align__(16) unsigned short kb[2][64 * 64];
    __shared__ __align__(16) unsigned short vb[2][64 * 64];
    __shared__ __align__(16) unsigned short pl[8][16][80];

    int lane = threadIdx.x & 63;
    int wave = threadIdx.x >> 6;
    int lrow = lane & 15, lgrp = lane >> 4;

    // XCD-aware remap: id&7 = xcd, 4 bh per xcd
    int id = blockIdx.x;
    int xcd = id & 7;
    int loc = id >> 3;            // 0..63
    int bh = xcd * 4 + (loc >> 4);
    int qb = loc & 15;
    int b = bh >> 3, h = bh & 7;
    int qw = qb * 128 + wave * 16;   // this wave's 16 q rows

    const unsigned short* qrow = Q + ((size_t)bh * NS + qw + lrow) * NDK + lgrp * 8;
    bf16x8 aq0 = *(const bf16x8*)(qrow);
    bf16x8 aq1 = *(const bf16x8*)(qrow + 32);

    const unsigned short* kbase = K + (size_t)bh * NS * NDK;
    const unsigned short* vbase = VT + (size_t)bh * NDK * NS;
    const unsigned long long* bmb = bm + (size_t)b * NS * (NS / 64);
    int bmoff[4];
#pragma unroll
    for (int j = 0; j < 4; j++) bmoff[j] = (qw + lgrp * 4 + j) * (NS / 64);

    int rl = lane >> 3, cc = lane & 7;      // staging: slab row, chunk
    int cs = (cc ^ rl) * 8;                 // swizzled source chunk offset (ushorts)

    // ---- sweep 1: l = sum of unmasked exp2(sc) ----
    {
        const unsigned short* s0 = kbase + (size_t)(8 * wave + rl) * NDK + cs;
        gload_lds16(s0, &kb[0][wave * 512]);
    }
    unsigned long long wc[4], wn[4];
#pragma unroll
    for (int j = 0; j < 4; j++) wc[j] = bmb[bmoff[j]];
    __syncthreads();

    float lacc[4] = {0.f, 0.f, 0.f, 0.f};
    for (int t = 0; t < NT; t++) {
        int buf = t & 1;
        int tn = (t + 1 < NT) ? t + 1 : t;
        if (t + 1 < NT) {
            const unsigned short* s0 = kbase + (size_t)(tn * 64 + 8 * wave + rl) * NDK + cs;
            gload_lds16(s0, &kb[buf ^ 1][wave * 512]);
        }
#pragma unroll
        for (int j = 0; j < 4; j++) wn[j] = bmb[bmoff[j] + tn];

        f32x4 sc[4] = {{0.f,0.f,0.f,0.f},{0.f,0.f,0.f,0.f},{0.f,0.f,0.f,0.f},{0.f,0.f,0.f,0.f}};
        __builtin_amdgcn_s_setprio(1);
#pragma unroll
        for (int n = 0; n < 4; n++) {
            int R = n * 16 + lrow;
            bf16x8 b0 = *(const bf16x8*)&kb[buf][R * 64 + ((lgrp ^ (lrow & 7)) * 8)];
            bf16x8 b1 = *(const bf16x8*)&kb[buf][R * 64 + (((4 + lgrp) ^ (lrow & 7)) * 8)];
            sc[n] = __builtin_amdgcn_mfma_f32_16x16x32_bf16(aq0, b0, sc[n], 0, 0, 0);
            sc[n] = __builtin_amdgcn_mfma_f32_16x16x32_bf16(aq1, b1, sc[n], 0, 0, 0);
        }
        __builtin_amdgcn_s_setprio(0);
#pragma unroll
        for (int j = 0; j < 4; j++) {
            uint32_t wlo = (uint32_t)wc[j], whi = (uint32_t)(wc[j] >> 32);
#pragma unroll
            for (int n = 0; n < 4; n++) {
                uint32_t bit = ((n < 2 ? wlo : whi) >> ((n & 1) * 16 + lrow)) & 1u;
                float e = exp2_fast(sc[n][j]);
                lacc[j] += bit ? 0.f : e;
            }
        }
#pragma unroll
        for (int j = 0; j < 4; j++) wc[j] = wn[j];
        __syncthreads();
    }
    float li[4];
#pragma unroll
    for (int j = 0; j < 4; j++) {
        float l = lacc[j];
        l += __shfl_xor(l, 1);
        l += __shfl_xor(l, 2);
        l += __shfl_xor(l, 4);
        l += __shfl_xor(l, 8);
        li[j] = -__log2f(l);
    }

    // ---- sweep 2: recompute, write normalized attn (deferred 1 tile), accumulate O ----
    {
        const unsigned short* s0 = kbase + (size_t)(8 * wave + rl) * NDK + cs;
        gload_lds16(s0, &kb[0][wave * 512]);
        const unsigned short* s1 = vbase + (size_t)(8 * wave + rl) * NS + cs;
        gload_lds16(s1, &vb[0][wave * 512]);
    }
#pragma unroll
    for (int j = 0; j < 4; j++) wc[j] = bmb[bmoff[j]];
    __syncthreads();

    f32x4 accO[4] = {{0.f,0.f,0.f,0.f},{0.f,0.f,0.f,0.f},{0.f,0.f,0.f,0.f},{0.f,0.f,0.f,0.f}};
    float* aout = attn_out + (size_t)bh * NS * NS;
    float* abase[4];
#pragma unroll
    for (int j = 0; j < 4; j++) abase[j] = aout + (size_t)(qw + lgrp * 4 + j) * NS + lrow;

    float pst[4][4];
    for (int t = 0; t < NT; t++) {
        int buf = t & 1;
        int tn = (t + 1 < NT) ? t + 1 : t;
        // deferred stores for tile t-1: a full tile of compute hides the store tail
        if (t > 0) {
            int ktp = (t - 1) * 64;
#pragma unroll
            for (int n = 0; n < 4; n++)
#pragma unroll
                for (int j = 0; j < 4; j++)
                    abase[j][ktp + n * 16] = pst[n][j];
        }
        if (t + 1 < NT) {
            const unsigned short* s0 = kbase + (size_t)(tn * 64 + 8 * wave + rl) * NDK + cs;
            gload_lds16(s0, &kb[buf ^ 1][wave * 512]);
            const unsigned short* s1 = vbase + (size_t)(8 * wave + rl) * NS + tn * 64 + cs;
            gload_lds16(s1, &vb[buf ^ 1][wave * 512]);
        }
#pragma unroll
        for (int j = 0; j < 4; j++) wn[j] = bmb[bmoff[j] + tn];

        f32x4 sc[4] = {{0.f,0.f,0.f,0.f},{0.f,0.f,0.f,0.f},{0.f,0.f,0.f,0.f},{0.f,0.f,0.f,0.f}};
        __builtin_amdgcn_s_setprio(1);
#pragma unroll
        for (int n = 0; n < 4; n++) {
            int R = n * 16 + lrow;
            bf16x8 b0 = *(const bf16x8*)&kb[buf][R * 64 + ((lgrp ^ (lrow & 7)) * 8)];
            bf16x8 b1 = *(const bf16x8*)&kb[buf][R * 64 + (((4 + lgrp) ^ (lrow & 7)) * 8)];
            sc[n] = __builtin_amdgcn_mfma_f32_16x16x32_bf16(aq0, b0, sc[n], 0, 0, 0);
            sc[n] = __builtin_amdgcn_mfma_f32_16x16x32_bf16(aq1, b1, sc[n], 0, 0, 0);
        }
        __builtin_amdgcn_s_setprio(0);
#pragma unroll
        for (int j = 0; j < 4; j++) {
            uint32_t wlo = (uint32_t)wc[j], whi = (uint32_t)(wc[j] >> 32);
#pragma unroll
            for (int n = 0; n < 4; n++) {
                uint32_t bit = ((n < 2 ? wlo : whi) >> ((n & 1) * 16 + lrow)) & 1u;
                float p = bit ? 0.f : exp2_fast(sc[n][j] + li[j]);   // normalized
                pst[n][j] = p;
                pl[wave][lgrp * 4 + j][n * 16 + lrow] = f2bf_fast(p);
            }
        }
        __builtin_amdgcn_s_setprio(1);
#pragma unroll
        for (int step = 0; step < 2; step++) {
            bf16x8 ap = *(const bf16x8*)&pl[wave][lrow][step * 32 + lgrp * 8];
#pragma unroll
            for (int n = 0; n < 4; n++) {
                int R = n * 16 + lrow;
                bf16x8 bv = *(const bf16x8*)&vb[buf][R * 64 + (((4 * step + lgrp) ^ (lrow & 7)) * 8)];
                accO[n] = __builtin_amdgcn_mfma_f32_16x16x32_bf16(ap, bv, accO[n], 0, 0, 0);
            }
        }
        __builtin_amdgcn_s_setprio(0);
#pragma unroll
        for (int j = 0; j < 4; j++) wc[j] = wn[j];
        __syncthreads();
    }
    // flush last tile's stores
    {
        int ktp = (NT - 1) * 64;
#pragma unroll
        for (int n = 0; n < 4; n++)
#pragma unroll
            for (int j = 0; j < 4; j++)
                abase[j][ktp + n * 16] = pst[n][j];
    }

#pragma unroll
    for (int n = 0; n < 4; n++)
#pragma unroll
        for (int j = 0; j < 4; j++) {
            int qi = qw + lgrp * 4 + j;
            Ob[((size_t)b * NS + qi) * ND + h * NDK + n * 16 + lrow] = accO[n][j];
        }
}

// ---------------- residual + LayerNorm (OpenNMT: unbiased std, eps on std) ----------------
__global__ __launch_bounds__(256) void ln_kernel(const float* __restrict__ Ob,
                                                 const float* __restrict__ query,
                                                 const float* __restrict__ a2,
                                                 const float* __restrict__ b2,
                                                 float* __restrict__ out) {
    int row = blockIdx.x * 4 + (threadIdx.x >> 6);
    int lane = threadIdx.x & 63;
    const float4* orow = (const float4*)(Ob + (size_t)row * ND);
    const float4* qrow = (const float4*)(query + (size_t)row * ND);
    float4 v[2];
    float sum = 0.f;
#pragma unroll
    for (int t = 0; t < 2; t++) {
        float4 o = orow[lane + t * 64];
        float4 q = qrow[lane + t * 64];
        v[t].x = o.x + q.x; v[t].y = o.y + q.y; v[t].z = o.z + q.z; v[t].w = o.w + q.w;
        sum += v[t].x + v[t].y + v[t].z + v[t].w;
    }
#pragma unroll
    for (int s = 1; s < 64; s <<= 1) sum += __shfl_xor(sum, s);
    float mu = sum * (1.f / ND);
    float sq = 0.f;
#pragma unroll
    for (int t = 0; t < 2; t++) {
        float dx = v[t].x - mu, dy = v[t].y - mu, dz = v[t].z - mu, dw = v[t].w - mu;
        sq += dx * dx + dy * dy + dz * dz + dw * dw;
    }
#pragma unroll
    for (int s = 1; s < 64; s <<= 1) sq += __shfl_xor(sq, s);
    float var = sq * (1.f / (ND - 1));
    float inv = 1.f / (sqrtf(var) + 1e-6f);
    float4* orow_out = (float4*)(out + (size_t)row * ND);
#pragma unroll
    for (int t = 0; t < 2; t++) {
        float4 g = ((const float4*)a2)[lane + t * 64];
        float4 bb = ((const float4*)b2)[lane + t * 64];
        float4 r;
        r.x = g.x * (v[t].x - mu) * inv + bb.x;
        r.y = g.y * (v[t].y - mu) * inv + bb.y;
        r.z = g.z * (v[t].z - mu) * inv + bb.z;
        r.w = g.w * (v[t].w - mu) * inv + bb.w;
        orow_out[lane + t * 64] = r;
    }
}

extern "C" void kernel_launch(void* const* d_in, const int* in_sizes, int n_in,
                              void* d_out, int out_size, void* d_ws, size_t ws_size,
                              hipStream_t stream) {
    const float* key   = (const float*)d_in[0];
    const float* value = (const float*)d_in[1];
    const float* query = (const float*)d_in[2];
    const int*   mask  = (const int*)d_in[3];
    const float* Wk = (const float*)d_in[4];
    const float* bk = (const float*)d_in[5];
    const float* Wv = (const float*)d_in[6];
    const float* bv = (const float*)d_in[7];
    const float* Wq = (const float*)d_in[8];
    const float* bq = (const float*)d_in[9];
    const float* a2 = (const float*)d_in[10];
    const float* b2 = (const float*)d_in[11];

    const size_t nX = (size_t)NB * NS * ND;   // 4,194,304
    const size_t nW = (size_t)ND * ND;        // 262,144
    const int    nBMw = NB * NS * NS / 64;    // 262,144 uint64 words

    unsigned short* xq  = (unsigned short*)d_ws;  // bf16 buffers
    unsigned short* xk  = xq + nX;
    unsigned short* xv  = xk + nX;
    unsigned short* wqb = xv + nX;
    unsigned short* wkb = wqb + nW;
    unsigned short* wvb = wkb + nW;
    unsigned short* Qw  = wvb + nW;               // [BH][S][dk]
    unsigned short* Kw  = Qw + nX;                // [BH][S][dk]
    unsigned short* VTw = Kw + nX;                // [BH][dk][S]
    float* Ow = (float*)(VTw + nX);               // [B][S][D] fp32
    unsigned long long* bmw = (unsigned long long*)(Ow + nX);  // bitmask, 2 MB

    bitmask_kernel<<<2048, 256, 0, stream>>>(mask, bmw, nBMw);

    cvt3_kernel<<<dim3((int)(nX / 4 / 256), 3), 256, 0, stream>>>(
        (const float4*)query, (const float4*)key, (const float4*)value,
        (ushort4*)xq, (ushort4*)xk, (ushort4*)xv, (int)(nX / 4));
    cvt3_kernel<<<dim3((int)(nW / 4 / 256), 3), 256, 0, stream>>>(
        (const float4*)Wq, (const float4*)Wk, (const float4*)Wv,
        (ushort4*)wqb, (ushort4*)wkb, (ushort4*)wvb, (int)(nW / 4));

    proj_kernel<<<dim3(128, 8, 3), 256, 0, stream>>>(xq, xk, xv, wqb, wkb, wvb,
                                                     bq, bk, bv, Qw, Kw, VTw);

    float* attn_out = (float*)d_out + nX;  // res occupies first nX floats
    attn_kernel<<<512, 512, 0, stream>>>(Qw, Kw, VTw, bmw, attn_out, Ow);

    ln_kernel<<<2048, 256, 0, stream>>>(Ow, query, a2, b2, (float*)d_out);
}

// Round 6
// 360.133 us; speedup vs baseline: 1.1049x; 1.1049x over previous
//
#include <hip/hip_runtime.h>
#include <stdint.h>

typedef float f32x4 __attribute__((ext_vector_type(4)));
typedef short bf16x8 __attribute__((ext_vector_type(8)));

constexpr int NB = 4;      // batch
constexpr int NS = 2048;   // sequence
constexpr int ND = 512;    // model dim
constexpr int NH = 8;      // heads
constexpr int NDK = 64;    // head dim
constexpr int NT = NS / 64;  // 32 K-tiles
constexpr float QSCALE = 0.125f * 1.44269504088896340736f;  // 1/sqrt(dk) * log2(e)

static __device__ __forceinline__ unsigned short f2bf(float f) {
    union { float f; uint32_t u; } v; v.f = f;
    uint32_t r = (v.u + 0x7FFFu + ((v.u >> 16) & 1u)) >> 16;
    return (unsigned short)r;
}
static __device__ __forceinline__ unsigned short f2bf_fast(float f) {
    union { float f; uint32_t u; } v; v.f = f;
    return (unsigned short)((v.u + 0x8000u) >> 16);
}
static __device__ __forceinline__ float exp2_fast(float x) {
#if __has_builtin(__builtin_amdgcn_exp2f)
    return __builtin_amdgcn_exp2f(x);
#else
    return exp2f(x);
#endif
}

// async global->LDS, 16B per lane; dest is wave-uniform base (+lane*16 by HW)
static __device__ __forceinline__ void gload_lds16(const void* g, void* l) {
    __builtin_amdgcn_global_load_lds((const __attribute__((address_space(1))) void*)g,
                                     (__attribute__((address_space(3))) void*)l, 16, 0, 0);
}

// ---------------- fp32 -> bf16 convert (3 tensors fused) ----------------
__global__ __launch_bounds__(256) void cvt3_kernel(const float4* __restrict__ a,
                                                   const float4* __restrict__ b,
                                                   const float4* __restrict__ c,
                                                   ushort4* __restrict__ oa,
                                                   ushort4* __restrict__ ob,
                                                   ushort4* __restrict__ oc, int n4) {
    int which = blockIdx.y;
    const float4* in = which == 0 ? a : which == 1 ? b : c;
    ushort4* out = which == 0 ? oa : which == 1 ? ob : oc;
    int i = blockIdx.x * blockDim.x + threadIdx.x;
    if (i >= n4) return;
    float4 v = in[i];
    ushort4 o;
    o.x = f2bf(v.x); o.y = f2bf(v.y); o.z = f2bf(v.z); o.w = f2bf(v.w);
    out[i] = o;
}

// ---------------- mask int32 -> bitmask (1 bit per element) ----------------
__global__ __launch_bounds__(256) void bitmask_kernel(const int* __restrict__ mask,
                                                      unsigned long long* __restrict__ bm,
                                                      int nwords) {
    int lane = threadIdx.x & 63;
    int wave = threadIdx.x >> 6;
    int wgid = blockIdx.x * 4 + wave;
    int nw = gridDim.x * 4;
    for (int c = wgid; c < nwords; c += nw) {
        int v = mask[(size_t)c * 64 + lane];
        unsigned long long bits = __ballot(v != 0);
        if (lane == 0) bm[c] = bits;
    }
}

// ---------------- fused projections: z=0 Q (scale QSCALE), z=1 K, z=2 V (transposed out) -----
__global__ __launch_bounds__(256) void proj_kernel(const unsigned short* __restrict__ xq,
                                                   const unsigned short* __restrict__ xk,
                                                   const unsigned short* __restrict__ xv,
                                                   const unsigned short* __restrict__ wq,
                                                   const unsigned short* __restrict__ wk,
                                                   const unsigned short* __restrict__ wv,
                                                   const float* __restrict__ bq,
                                                   const float* __restrict__ bk,
                                                   const float* __restrict__ bv,
                                                   unsigned short* __restrict__ Qw,
                                                   unsigned short* __restrict__ Kw,
                                                   unsigned short* __restrict__ VTw) {
    int z = blockIdx.z;
    const unsigned short* X = z == 0 ? xq : z == 1 ? xk : xv;
    const unsigned short* W = z == 0 ? wq : z == 1 ? wk : wv;
    const float* bias = z == 0 ? bq : z == 1 ? bk : bv;
    unsigned short* out = z == 0 ? Qw : z == 1 ? Kw : VTw;
    float scale = z == 0 ? QSCALE : 1.0f;
    int vtrans = (z == 2);

    int lane = threadIdx.x & 63;
    int wave = threadIdx.x >> 6;
    int lrow = lane & 15, lgrp = lane >> 4;
    int m0 = blockIdx.x * 64 + wave * 16;
    int n0 = blockIdx.y * 64;

    f32x4 acc[4] = {{0.f,0.f,0.f,0.f},{0.f,0.f,0.f,0.f},{0.f,0.f,0.f,0.f},{0.f,0.f,0.f,0.f}};
    const unsigned short* xrow = X + (size_t)(m0 + lrow) * ND;
    for (int k = 0; k < ND; k += 32) {
        bf16x8 a = *(const bf16x8*)(xrow + k + lgrp * 8);
#pragma unroll
        for (int n = 0; n < 4; n++) {
            bf16x8 b = *(const bf16x8*)(W + (size_t)(n0 + n * 16 + lrow) * ND + k + lgrp * 8);
            acc[n] = __builtin_amdgcn_mfma_f32_16x16x32_bf16(a, b, acc[n], 0, 0, 0);
        }
    }
#pragma unroll
    for (int n = 0; n < 4; n++) {
        int col = n0 + n * 16 + lrow;
        int h = col >> 6, d = col & 63;
        float bv_ = bias[col];
#pragma unroll
        for (int j = 0; j < 4; j++) {
            int m = m0 + lgrp * 4 + j;
            int bidx = m >> 11, s = m & (NS - 1);
            float y = (acc[n][j] + bv_) * scale;
            size_t off = vtrans ? ((size_t)(bidx * NH + h) * NDK + d) * NS + s
                                : ((size_t)(bidx * NH + h) * NS + s) * NDK + d;
            out[off] = f2bf(y);
        }
    }
}

// ---------------- attention ----------------
// 512 threads = 8 waves; block owns 128 q-rows, full K range. Q pre-scaled by log2e/8,
// so p = exp2(sc + li[row]), li = -log2(sum). K/V staged in LDS via global_load_lds,
// double-buffered, XOR-swizzled. Raw s_barrier + COUNTED vmcnt: the per-tile wait forces
// only the 2 prefetch loads; attn stores float across barriers and retire under compute.
__global__ __launch_bounds__(512) void attn_kernel(const unsigned short* __restrict__ Q,
                                                   const unsigned short* __restrict__ K,
                                                   const unsigned short* __restrict__ VT,
                                                   const unsigned long long* __restrict__ bm,
                                                   float* __restrict__ attn_out,
                                                   float* __restrict__ Ob) {
    __shared__ __align__(16) unsigned short kb[2][64 * 64];
    __shared__ __align__(16) unsigned short vb[2][64 * 64];
    __shared__ __align__(16) unsigned short pl[8][16][80];

    int lane = threadIdx.x & 63;
    int wave = threadIdx.x >> 6;
    int lrow = lane & 15, lgrp = lane >> 4;

    // XCD-aware remap: id&7 = xcd, 4 bh per xcd
    int id = blockIdx.x;
    int xcd = id & 7;
    int loc = id >> 3;            // 0..63
    int bh = xcd * 4 + (loc >> 4);
    int qb = loc & 15;
    int b = bh >> 3, h = bh & 7;
    int qw = qb * 128 + wave * 16;   // this wave's 16 q rows

    const unsigned short* qrow = Q + ((size_t)bh * NS + qw + lrow) * NDK + lgrp * 8;
    bf16x8 aq0 = *(const bf16x8*)(qrow);
    bf16x8 aq1 = *(const bf16x8*)(qrow + 32);

    const unsigned short* kbase = K + (size_t)bh * NS * NDK;
    const unsigned short* vbase = VT + (size_t)bh * NDK * NS;
    const unsigned long long* bmb = bm + (size_t)b * NS * (NS / 64);
    int bmoff[4];
#pragma unroll
    for (int j = 0; j < 4; j++) bmoff[j] = (qw + lgrp * 4 + j) * (NS / 64);

    int rl = lane >> 3, cc = lane & 7;      // staging: slab row, chunk
    int cs = (cc ^ rl) * 8;                 // swizzled source chunk offset (ushorts)

    // ---- sweep 1: l = sum of unmasked exp2(sc) ----
    {
        const unsigned short* s0 = kbase + (size_t)(8 * wave + rl) * NDK + cs;
        gload_lds16(s0, &kb[0][wave * 512]);
    }
    unsigned long long wc[4], wn[4];
#pragma unroll
    for (int j = 0; j < 4; j++) wc[j] = bmb[bmoff[j]];
    asm volatile("s_waitcnt vmcnt(0)" ::: "memory");
    __builtin_amdgcn_s_barrier();

    float lacc[4] = {0.f, 0.f, 0.f, 0.f};
    for (int t = 0; t < NT; t++) {
        int buf = t & 1;
        int tn = (t + 1 < NT) ? t + 1 : t;
        if (t + 1 < NT) {
            const unsigned short* s0 = kbase + (size_t)(tn * 64 + 8 * wave + rl) * NDK + cs;
            gload_lds16(s0, &kb[buf ^ 1][wave * 512]);
        }
#pragma unroll
        for (int j = 0; j < 4; j++) wn[j] = bmb[bmoff[j] + tn];

        f32x4 sc[4] = {{0.f,0.f,0.f,0.f},{0.f,0.f,0.f,0.f},{0.f,0.f,0.f,0.f},{0.f,0.f,0.f,0.f}};
        __builtin_amdgcn_s_setprio(1);
#pragma unroll
        for (int n = 0; n < 4; n++) {
            int R = n * 16 + lrow;
            bf16x8 b0 = *(const bf16x8*)&kb[buf][R * 64 + ((lgrp ^ (lrow & 7)) * 8)];
            bf16x8 b1 = *(const bf16x8*)&kb[buf][R * 64 + (((4 + lgrp) ^ (lrow & 7)) * 8)];
            sc[n] = __builtin_amdgcn_mfma_f32_16x16x32_bf16(aq0, b0, sc[n], 0, 0, 0);
            sc[n] = __builtin_amdgcn_mfma_f32_16x16x32_bf16(aq1, b1, sc[n], 0, 0, 0);
        }
        __builtin_amdgcn_s_setprio(0);
#pragma unroll
        for (int j = 0; j < 4; j++) {
            uint32_t wlo = (uint32_t)wc[j], whi = (uint32_t)(wc[j] >> 32);
#pragma unroll
            for (int n = 0; n < 4; n++) {
                uint32_t bit = ((n < 2 ? wlo : whi) >> ((n & 1) * 16 + lrow)) & 1u;
                float e = exp2_fast(sc[n][j]);
                lacc[j] += bit ? 0.f : e;
            }
        }
#pragma unroll
        for (int j = 0; j < 4; j++) wc[j] = wn[j];
        if (t + 1 < NT) {
            // only the 1 prefetch load can be outstanding; it had the whole tile to land
            asm volatile("s_waitcnt vmcnt(0)" ::: "memory");
            __builtin_amdgcn_s_barrier();
        }
    }
    float li[4];
#pragma unroll
    for (int j = 0; j < 4; j++) {
        float l = lacc[j];
        l += __shfl_xor(l, 1);
        l += __shfl_xor(l, 2);
        l += __shfl_xor(l, 4);
        l += __shfl_xor(l, 8);
        li[j] = -__log2f(l);
    }

    // ---- sweep 2: recompute, write normalized attn, accumulate O ----
    {
        const unsigned short* s0 = kbase + (size_t)(8 * wave + rl) * NDK + cs;
        gload_lds16(s0, &kb[0][wave * 512]);
        const unsigned short* s1 = vbase + (size_t)(8 * wave + rl) * NS + cs;
        gload_lds16(s1, &vb[0][wave * 512]);
    }
#pragma unroll
    for (int j = 0; j < 4; j++) wc[j] = bmb[bmoff[j]];
    asm volatile("s_waitcnt vmcnt(0)" ::: "memory");
    __builtin_amdgcn_s_barrier();

    f32x4 accO[4] = {{0.f,0.f,0.f,0.f},{0.f,0.f,0.f,0.f},{0.f,0.f,0.f,0.f},{0.f,0.f,0.f,0.f}};
    float* aout = attn_out + (size_t)bh * NS * NS;
    float* abase[4];
#pragma unroll
    for (int j = 0; j < 4; j++) abase[j] = aout + (size_t)(qw + lgrp * 4 + j) * NS + lrow;

    for (int t = 0; t < NT; t++) {
        int buf = t & 1;
        int kt = t * 64;
        int tn = (t + 1 < NT) ? t + 1 : t;
        if (t + 1 < NT) {
            const unsigned short* s0 = kbase + (size_t)(tn * 64 + 8 * wave + rl) * NDK + cs;
            gload_lds16(s0, &kb[buf ^ 1][wave * 512]);
            const unsigned short* s1 = vbase + (size_t)(8 * wave + rl) * NS + tn * 64 + cs;
            gload_lds16(s1, &vb[buf ^ 1][wave * 512]);
        }
#pragma unroll
        for (int j = 0; j < 4; j++) wn[j] = bmb[bmoff[j] + tn];

        f32x4 sc[4] = {{0.f,0.f,0.f,0.f},{0.f,0.f,0.f,0.f},{0.f,0.f,0.f,0.f},{0.f,0.f,0.f,0.f}};
        __builtin_amdgcn_s_setprio(1);
#pragma unroll
        for (int n = 0; n < 4; n++) {
            int R = n * 16 + lrow;
            bf16x8 b0 = *(const bf16x8*)&kb[buf][R * 64 + ((lgrp ^ (lrow & 7)) * 8)];
            bf16x8 b1 = *(const bf16x8*)&kb[buf][R * 64 + (((4 + lgrp) ^ (lrow & 7)) * 8)];
            sc[n] = __builtin_amdgcn_mfma_f32_16x16x32_bf16(aq0, b0, sc[n], 0, 0, 0);
            sc[n] = __builtin_amdgcn_mfma_f32_16x16x32_bf16(aq1, b1, sc[n], 0, 0, 0);
        }
        __builtin_amdgcn_s_setprio(0);
#pragma unroll
        for (int j = 0; j < 4; j++) {
            uint32_t wlo = (uint32_t)wc[j], whi = (uint32_t)(wc[j] >> 32);
#pragma unroll
            for (int n = 0; n < 4; n++) {
                uint32_t bit = ((n < 2 ? wlo : whi) >> ((n & 1) * 16 + lrow)) & 1u;
                float p = bit ? 0.f : exp2_fast(sc[n][j] + li[j]);   // normalized
                abase[j][kt + n * 16] = p;
                pl[wave][lgrp * 4 + j][n * 16 + lrow] = f2bf_fast(p);
            }
        }
        __builtin_amdgcn_s_setprio(1);
#pragma unroll
        for (int step = 0; step < 2; step++) {
            bf16x8 ap = *(const bf16x8*)&pl[wave][lrow][step * 32 + lgrp * 8];
#pragma unroll
            for (int n = 0; n < 4; n++) {
                int R = n * 16 + lrow;
                bf16x8 bv = *(const bf16x8*)&vb[buf][R * 64 + (((4 * step + lgrp) ^ (lrow & 7)) * 8)];
                accO[n] = __builtin_amdgcn_mfma_f32_16x16x32_bf16(ap, bv, accO[n], 0, 0, 0);
            }
        }
        __builtin_amdgcn_s_setprio(0);
#pragma unroll
        for (int j = 0; j < 4; j++) wc[j] = wn[j];
        if (t + 1 < NT) {
            // force only the 2 prefetch loads (issued before the 16 p-stores) to complete;
            // the stores stay in flight across the barrier and retire under the next tile
            asm volatile("s_waitcnt vmcnt(16)" ::: "memory");
            __builtin_amdgcn_s_barrier();
        }
    }

#pragma unroll
    for (int n = 0; n < 4; n++)
#pragma unroll
        for (int j = 0; j < 4; j++) {
            int qi = qw + lgrp * 4 + j;
            Ob[((size_t)b * NS + qi) * ND + h * NDK + n * 16 + lrow] = accO[n][j];
        }
}

// ---------------- residual + LayerNorm (OpenNMT: unbiased std, eps on std) ----------------
__global__ __launch_bounds__(256) void ln_kernel(const float* __restrict__ Ob,
                                                 const float* __restrict__ query,
                                                 const float* __restrict__ a2,
                                                 const float* __restrict__ b2,
                                                 float* __restrict__ out) {
    int row = blockIdx.x * 4 + (threadIdx.x >> 6);
    int lane = threadIdx.x & 63;
    const float4* orow = (const float4*)(Ob + (size_t)row * ND);
    const float4* qrow = (const float4*)(query + (size_t)row * ND);
    float4 v[2];
    float sum = 0.f;
#pragma unroll
    for (int t = 0; t < 2; t++) {
        float4 o = orow[lane + t * 64];
        float4 q = qrow[lane + t * 64];
        v[t].x = o.x + q.x; v[t].y = o.y + q.y; v[t].z = o.z + q.z; v[t].w = o.w + q.w;
        sum += v[t].x + v[t].y + v[t].z + v[t].w;
    }
#pragma unroll
    for (int s = 1; s < 64; s <<= 1) sum += __shfl_xor(sum, s);
    float mu = sum * (1.f / ND);
    float sq = 0.f;
#pragma unroll
    for (int t = 0; t < 2; t++) {
        float dx = v[t].x - mu, dy = v[t].y - mu, dz = v[t].z - mu, dw = v[t].w - mu;
        sq += dx * dx + dy * dy + dz * dz + dw * dw;
    }
#pragma unroll
    for (int s = 1; s < 64; s <<= 1) sq += __shfl_xor(sq, s);
    float var = sq * (1.f / (ND - 1));
    float inv = 1.f / (sqrtf(var) + 1e-6f);
    float4* orow_out = (float4*)(out + (size_t)row * ND);
#pragma unroll
    for (int t = 0; t < 2; t++) {
        float4 g = ((const float4*)a2)[lane + t * 64];
        float4 bb = ((const float4*)b2)[lane + t * 64];
        float4 r;
        r.x = g.x * (v[t].x - mu) * inv + bb.x;
        r.y = g.y * (v[t].y - mu) * inv + bb.y;
        r.z = g.z * (v[t].z - mu) * inv + bb.z;
        r.w = g.w * (v[t].w - mu) * inv + bb.w;
        orow_out[lane + t * 64] = r;
    }
}

extern "C" void kernel_launch(void* const* d_in, const int* in_sizes, int n_in,
                              void* d_out, int out_size, void* d_ws, size_t ws_size,
                              hipStream_t stream) {
    const float* key   = (const float*)d_in[0];
    const float* value = (const float*)d_in[1];
    const float* query = (const float*)d_in[2];
    const int*   mask  = (const int*)d_in[3];
    const float* Wk = (const float*)d_in[4];
    const float* bk = (const float*)d_in[5];
    const float* Wv = (const float*)d_in[6];
    const float* bv = (const float*)d_in[7];
    const float* Wq = (const float*)d_in[8];
    const float* bq = (const float*)d_in[9];
    const float* a2 = (const float*)d_in[10];
    const float* b2 = (const float*)d_in[11];

    const size_t nX = (size_t)NB * NS * ND;   // 4,194,304
    const size_t nW = (size_t)ND * ND;        // 262,144
    const int    nBMw = NB * NS * NS / 64;    // 262,144 uint64 words

    unsigned short* xq  = (unsigned short*)d_ws;  // bf16 buffers
    unsigned short* xk  = xq + nX;
    unsigned short* xv  = xk + nX;
    unsigned short* wqb = xv + nX;
    unsigned short* wkb = wqb + nW;
    unsigned short* wvb = wkb + nW;
    unsigned short* Qw  = wvb + nW;               // [BH][S][dk]
    unsigned short* Kw  = Qw + nX;                // [BH][S][dk]
    unsigned short* VTw = Kw + nX;                // [BH][dk][S]
    float* Ow = (float*)(VTw + nX);               // [B][S][D] fp32
    unsigned long long* bmw = (unsigned long long*)(Ow + nX);  // bitmask, 2 MB

    bitmask_kernel<<<2048, 256, 0, stream>>>(mask, bmw, nBMw);

    cvt3_kernel<<<dim3((int)(nX / 4 / 256), 3), 256, 0, stream>>>(
        (const float4*)query, (const float4*)key, (const float4*)value,
        (ushort4*)xq, (ushort4*)xk, (ushort4*)xv, (int)(nX / 4));
    cvt3_kernel<<<dim3((int)(nW / 4 / 256), 3), 256, 0, stream>>>(
        (const float4*)Wq, (const float4*)Wk, (const float4*)Wv,
        (ushort4*)wqb, (ushort4*)wkb, (ushort4*)wvb, (int)(nW / 4));

    proj_kernel<<<dim3(128, 8, 3), 256, 0, stream>>>(xq, xk, xv, wqb, wkb, wvb,
                                                     bq, bk, bv, Qw, Kw, VTw);

    float* attn_out = (float*)d_out + nX;  // res occupies first nX floats
    attn_kernel<<<512, 512, 0, stream>>>(Qw, Kw, VTw, bmw, attn_out, Ow);

    ln_kernel<<<2048, 256, 0, stream>>>(Ow, query, a2, b2, (float*)d_out);
}